// Round 1
// baseline (912.118 us; speedup 1.0000x reference)
//
#include <hip/hip_runtime.h>

typedef unsigned short u16;
typedef __attribute__((ext_vector_type(8))) short s16x8;
typedef __attribute__((ext_vector_type(4))) float f32x4;
typedef __attribute__((ext_vector_type(4))) unsigned short u16x4;

#define BATCH 4
#define SEQ 2048
#define DMODEL 1024
#define DM 2048
#define NST 16
#define NH 32
#define MROWS (BATCH*SEQ)      // 8192
#define NCHUNK 32
#define CLEN (SEQ/NCHUNK)      // 64

__device__ __forceinline__ u16 f2b(float f){
  union { float f; unsigned u; } v; v.f = f;
  unsigned r = (v.u + 0x7fffu + ((v.u >> 16) & 1u)) >> 16;   // RNE
  return (u16)r;
}
__device__ __forceinline__ float b2f(u16 u){
  union { unsigned u; float f; } v; v.u = ((unsigned)u) << 16;
  return v.f;
}

// ---------------- f32 -> bf16 bulk convert (vectorized, exact grids) -------
__global__ __launch_bounds__(256) void cvt_bf16(const float* __restrict__ s,
                                                u16* __restrict__ d){
  int i = blockIdx.x*256 + threadIdx.x;
  float4 v = ((const float4*)s)[i];
  u16x4 o; o[0]=f2b(v.x); o[1]=f2b(v.y); o[2]=f2b(v.z); o[3]=f2b(v.w);
  ((u16x4*)d)[i] = o;
}

// ---------------- B/C projection + row L2-normalize ------------------------
// one wave per row m: lanes 0..31 = 32 outputs (16 B + 16 C), khalf = lane>>5
__global__ __launch_bounds__(256) void bc_proj(
    const float* __restrict__ x,    // [MROWS, DMODEL] f32
    const float* __restrict__ Bw,   // [16, DMODEL]
    const float* __restrict__ Cw,   // [16, DMODEL]
    float* __restrict__ Bm, float* __restrict__ Cm)  // [MROWS,16]
{
  int wave = threadIdx.x >> 6;
  int lane = threadIdx.x & 63;
  int row  = blockIdx.x*4 + wave;
  int outn = lane & 15;
  int isC  = (lane >> 4) & 1;
  int khalf = lane >> 5;
  const float* wp = (isC ? Cw : Bw) + outn*DMODEL + khalf*(DMODEL/2);
  const float* xp = x + (size_t)row*DMODEL + khalf*(DMODEL/2);
  float acc = 0.f;
  for (int k = 0; k < DMODEL/2; k += 4){
    float4 xv = *(const float4*)&xp[k];
    float4 wv = *(const float4*)&wp[k];
    acc += xv.x*wv.x + xv.y*wv.y + xv.z*wv.z + xv.w*wv.w;
  }
  acc += __shfl_xor(acc, 32, 64);          // combine K halves
  float ss = acc*acc;                      // L2 over the 16-group
  ss += __shfl_xor(ss, 1, 64);
  ss += __shfl_xor(ss, 2, 64);
  ss += __shfl_xor(ss, 4, 64);
  ss += __shfl_xor(ss, 8, 64);
  float v = acc / fmaxf(sqrtf(ss), 1.0f);
  if (lane < 32){
    (isC ? Cm : Bm)[(size_t)row*NST + outn] = v;
  }
}

// ---------------- bf16 MFMA GEMM: C[M,N] = A[M,K] @ W[N,K]^T ---------------
// 128x128 block tile, BK=32, 4 waves x (64x64), 16x16x32 MFMA.
// EPI: 0 = store bf16 (x_ssm), 1 = +bias,clip,softplus,clip -> f32 (dt),
//      2 = store f32 (final out)
template<int EPI>
__global__ __launch_bounds__(256) void gemm_bt(
    const u16* __restrict__ A, const u16* __restrict__ W,
    float* __restrict__ Cf, u16* __restrict__ Cb,
    const float* __restrict__ bias, int N, int K)
{
  // pad 32 -> 40 shorts/row: stride 80B = 20 banks -> <=2-way conflicts (free)
  __shared__ u16 As[128*40];
  __shared__ u16 Ws[128*40];
  const int tid  = threadIdx.x;
  const int lane = tid & 63;
  const int wave = tid >> 6;
  const int qk = lane >> 4;     // k-quad: k = qk*8 + j
  const int rl = lane & 15;     // m/n within 16-tile
  const int wm = (wave >> 1) << 6;
  const int wn = (wave & 1) << 6;
  const int rowA0 = blockIdx.y * 128;
  const int rowW0 = blockIdx.x * 128;

  f32x4 acc[4][4];
#pragma unroll
  for (int mi=0;mi<4;mi++)
#pragma unroll
    for (int ni=0;ni<4;ni++)
      acc[mi][ni] = (f32x4){0.f,0.f,0.f,0.f};

  // staging: thread handles 8-short segment (row=tid>>2, col=(tid&3)*8) and row+64
  const int s0r = tid >> 2;
  const int s0c = (tid & 3) << 3;
  const u16* Ap = A + (size_t)(rowA0 + s0r)*K + s0c;
  const u16* Wp = W + (size_t)(rowW0 + s0r)*K + s0c;
  u16* AsP0 = &As[s0r*40 + s0c];
  u16* AsP1 = &As[(s0r+64)*40 + s0c];
  u16* WsP0 = &Ws[s0r*40 + s0c];
  u16* WsP1 = &Ws[(s0r+64)*40 + s0c];
  const size_t rstep = (size_t)64*K;

  for (int k0 = 0; k0 < K; k0 += 32){
    s16x8 a0 = *(const s16x8*)(Ap + k0);
    s16x8 a1 = *(const s16x8*)(Ap + rstep + k0);
    s16x8 w0 = *(const s16x8*)(Wp + k0);
    s16x8 w1 = *(const s16x8*)(Wp + rstep + k0);
    __syncthreads();
    *(s16x8*)AsP0 = a0;
    *(s16x8*)AsP1 = a1;
    *(s16x8*)WsP0 = w0;
    *(s16x8*)WsP1 = w1;
    __syncthreads();
    s16x8 af[4], bfr[4];
#pragma unroll
    for (int mi=0;mi<4;mi++) af[mi]  = *(const s16x8*)&As[(wm + mi*16 + rl)*40 + qk*8];
#pragma unroll
    for (int ni=0;ni<4;ni++) bfr[ni] = *(const s16x8*)&Ws[(wn + ni*16 + rl)*40 + qk*8];
#pragma unroll
    for (int mi=0;mi<4;mi++)
#pragma unroll
      for (int ni=0;ni<4;ni++)
        acc[mi][ni] = __builtin_amdgcn_mfma_f32_16x16x32_bf16(af[mi], bfr[ni], acc[mi][ni], 0, 0, 0);
  }

  // C/D layout: col = lane&15, row = (lane>>4)*4 + reg   [m89/m91 verified]
  const int crow = rowA0 + wm + qk*4;
  const int ccol = rowW0 + wn + rl;
#pragma unroll
  for (int mi=0;mi<4;mi++){
#pragma unroll
    for (int ni=0;ni<4;ni++){
#pragma unroll
      for (int r=0;r<4;r++){
        size_t idx = (size_t)(crow + mi*16 + r)*N + (ccol + ni*16);
        float v = acc[mi][ni][r];
        if constexpr (EPI == 0){
          Cb[idx] = f2b(v);
        } else if constexpr (EPI == 1){
          v += bias[ccol + ni*16];
          v = fminf(fmaxf(v, -10.f), 5.f);
          float sp = (v > 0.f) ? (v + log1pf(__expf(-v))) : log1pf(__expf(v));
          sp = fminf(fmaxf(sp, 1e-4f), 0.1f);
          Cf[idx] = sp;
        } else {
          Cf[idx] = v;
        }
      }
    }
  }
}

// ---------------- selective scan: 3-pass chunked --------------------------
// pass1: per (b,d,chunk) local scan from h=0 -> h_out[16], sum(dt)
__global__ __launch_bounds__(256) void scan_pass1(
    const float* __restrict__ dtb, const u16* __restrict__ xbf,
    const float* __restrict__ Bm, const float* __restrict__ A_log,
    float* __restrict__ hbuf, float* __restrict__ sdtb)
{
  int tid = blockIdx.x*256 + threadIdx.x;   // (b*NCHUNK + c)*DM + d
  int d  = tid & (DM-1);
  int bc = tid >> 11;
  int c  = bc & (NCHUNK-1);
  int b  = bc >> 5;
  int head = d >> 6;                        // DM/NH = 64 channels per head
  float mA2[NST];
#pragma unroll
  for (int n=0;n<NST;n++)
    mA2[n] = -__expf(A_log[head*NST+n]) * 1.44269504088896341f;  // -A*log2(e)
  float h[NST];
#pragma unroll
  for (int n=0;n<NST;n++) h[n] = 0.f;
  float sdt = 0.f;
  int rowbase = b*SEQ + c*CLEN;
  for (int t=0;t<CLEN;t++){
    int row = rowbase + t;
    float dtv = dtb[(size_t)row*DM + d];
    float xv  = b2f(xbf[(size_t)row*DM + d]);
    sdt += dtv;
    float dtx = dtv*xv;
    const float4* bp = (const float4*)&Bm[(size_t)row*NST];
    float4 b0=bp[0],b1=bp[1],b2=bp[2],b3=bp[3];
    float bb[NST] = {b0.x,b0.y,b0.z,b0.w, b1.x,b1.y,b1.z,b1.w,
                     b2.x,b2.y,b2.z,b2.w, b3.x,b3.y,b3.z,b3.w};
#pragma unroll
    for (int n=0;n<NST;n++)
      h[n] = exp2f(dtv*mA2[n])*h[n] + dtx*bb[n];
  }
  float* hp = &hbuf[((size_t)(b*DM + d)*NCHUNK + c)*NST];
#pragma unroll
  for (int n=0;n<NST;n++) hp[n] = h[n];
  sdtb[(size_t)(b*DM + d)*NCHUNK + c] = sdt;
}

// pass2: per (b,d,n) sequential prefix over chunks; in-place h_out -> h_in
__global__ __launch_bounds__(256) void scan_pass2(
    float* __restrict__ hbuf, const float* __restrict__ sdtb,
    const float* __restrict__ A_log)
{
  int tid = blockIdx.x*256 + threadIdx.x;   // b*DM*NST
  int n  = tid & (NST-1);
  int bd = tid >> 4;
  int d  = bd & (DM-1);
  int head = d >> 6;
  float mA2 = -__expf(A_log[head*NST+n]) * 1.44269504088896341f;
  float hrun = 0.f;
  size_t base = (size_t)bd*NCHUNK*NST + n;
  size_t sbase = (size_t)bd*NCHUNK;
  for (int c=0;c<NCHUNK;c++){
    float ho = hbuf[base + c*NST];
    float dp = exp2f(mA2 * sdtb[sbase + c]);   // exact chunk decay product
    hbuf[base + c*NST] = hrun;                  // h_in for chunk c
    hrun = dp*hrun + ho;
  }
}

// pass3: replay chunk with carried-in h, emit y_t (+ x*D) as bf16
__global__ __launch_bounds__(256) void scan_pass3(
    const float* __restrict__ dtb, const u16* __restrict__ xbf,
    const float* __restrict__ Bm, const float* __restrict__ Cm,
    const float* __restrict__ A_log, const float* __restrict__ Dvec,
    const float* __restrict__ hbuf, u16* __restrict__ ybf)
{
  int tid = blockIdx.x*256 + threadIdx.x;
  int d  = tid & (DM-1);
  int bc = tid >> 11;
  int c  = bc & (NCHUNK-1);
  int b  = bc >> 5;
  int head = d >> 6;
  float mA2[NST];
#pragma unroll
  for (int n=0;n<NST;n++)
    mA2[n] = -__expf(A_log[head*NST+n]) * 1.44269504088896341f;
  float h[NST];
  const float* hp = &hbuf[((size_t)(b*DM + d)*NCHUNK + c)*NST];
#pragma unroll
  for (int n=0;n<NST;n++) h[n] = hp[n];
  float Dv = Dvec[d];
  int rowbase = b*SEQ + c*CLEN;
  for (int t=0;t<CLEN;t++){
    int row = rowbase + t;
    float dtv = dtb[(size_t)row*DM + d];
    float xv  = b2f(xbf[(size_t)row*DM + d]);
    float dtx = dtv*xv;
    const float4* bp = (const float4*)&Bm[(size_t)row*NST];
    const float4* cp = (const float4*)&Cm[(size_t)row*NST];
    float4 b0=bp[0],b1=bp[1],b2=bp[2],b3=bp[3];
    float4 c0=cp[0],c1=cp[1],c2=cp[2],c3=cp[3];
    float bb[NST] = {b0.x,b0.y,b0.z,b0.w, b1.x,b1.y,b1.z,b1.w,
                     b2.x,b2.y,b2.z,b2.w, b3.x,b3.y,b3.z,b3.w};
    float cc[NST] = {c0.x,c0.y,c0.z,c0.w, c1.x,c1.y,c1.z,c1.w,
                     c2.x,c2.y,c2.z,c2.w, c3.x,c3.y,c3.z,c3.w};
    float y = 0.f;
#pragma unroll
    for (int n=0;n<NST;n++){
      h[n] = exp2f(dtv*mA2[n])*h[n] + dtx*bb[n];
      y += h[n]*cc[n];
    }
    y += xv*Dv;
    ybf[(size_t)row*DM + d] = f2b(y);
  }
}

// ---------------------------------------------------------------------------
extern "C" void kernel_launch(void* const* d_in, const int* in_sizes, int n_in,
                              void* d_out, int out_size, void* d_ws, size_t ws_size,
                              hipStream_t stream)
{
  (void)in_sizes; (void)n_in; (void)out_size; (void)ws_size;
  const float* x_norm    = (const float*)d_in[0];
  const float* x_proj_w  = (const float*)d_in[1];
  const float* dt_proj_w = (const float*)d_in[2];
  const float* dt_proj_b = (const float*)d_in[3];
  const float* B_proj_w  = (const float*)d_in[4];
  const float* C_proj_w  = (const float*)d_in[5];
  const float* A_log     = (const float*)d_in[6];
  const float* Dvec      = (const float*)d_in[7];
  const float* out_w     = (const float*)d_in[8];
  float* out = (float*)d_out;
  char* ws = (char*)d_ws;

  size_t off = 0;
  auto take = [&](size_t bytes)->void*{
    void* p = ws + off; off += (bytes + 255) & ~(size_t)255; return p;
  };
  u16*   xb    = (u16*)  take((size_t)MROWS*DMODEL*2);   // x_norm bf16
  u16*   wxb   = (u16*)  take((size_t)DM*DMODEL*2);      // x_proj_w bf16
  u16*   wdtb  = (u16*)  take((size_t)DM*DMODEL*2);      // dt_proj_w bf16
  u16*   woutb = (u16*)  take((size_t)DM*DM*2);          // out_proj_w bf16
  u16*   xssmb = (u16*)  take((size_t)MROWS*DM*2);       // x_ssm bf16
  float* dtf   = (float*)take((size_t)MROWS*DM*4);       // dt f32
  float* Bmb   = (float*)take((size_t)MROWS*NST*4);
  float* Cmb   = (float*)take((size_t)MROWS*NST*4);
  float* hbuf  = (float*)take((size_t)BATCH*DM*NCHUNK*NST*4);
  float* sdtb  = (float*)take((size_t)BATCH*DM*NCHUNK*4);
  u16*   ybf   = (u16*)  take((size_t)MROWS*DM*2);       // y bf16
  // total ~187 MB

  cvt_bf16<<<MROWS*DMODEL/1024, 256, 0, stream>>>(x_norm, xb);
  cvt_bf16<<<DM*DMODEL/1024,    256, 0, stream>>>(x_proj_w, wxb);
  cvt_bf16<<<DM*DMODEL/1024,    256, 0, stream>>>(dt_proj_w, wdtb);
  cvt_bf16<<<DM*DM/1024,        256, 0, stream>>>(out_w, woutb);
  bc_proj<<<MROWS/4, 256, 0, stream>>>(x_norm, B_proj_w, C_proj_w, Bmb, Cmb);
  gemm_bt<0><<<dim3(DM/128, MROWS/128), 256, 0, stream>>>(xb, wxb,  nullptr, xssmb, nullptr,   DM, DMODEL);
  gemm_bt<1><<<dim3(DM/128, MROWS/128), 256, 0, stream>>>(xb, wdtb, dtf,     nullptr, dt_proj_b, DM, DMODEL);
  scan_pass1<<<BATCH*NCHUNK*DM/256, 256, 0, stream>>>(dtf, xssmb, Bmb, A_log, hbuf, sdtb);
  scan_pass2<<<BATCH*DM*NST/256,    256, 0, stream>>>(hbuf, sdtb, A_log);
  scan_pass3<<<BATCH*NCHUNK*DM/256, 256, 0, stream>>>(dtf, xssmb, Bmb, Cmb, A_log, Dvec, hbuf, ybf);
  gemm_bt<2><<<dim3(DM/128, MROWS/128), 256, 0, stream>>>(ybf, woutb, out, nullptr, nullptr, DM, DM);
}

// Round 2
// 820.999 us; speedup vs baseline: 1.1110x; 1.1110x over previous
//
#include <hip/hip_runtime.h>

typedef unsigned short u16;
typedef __attribute__((ext_vector_type(8))) short s16x8;
typedef __attribute__((ext_vector_type(4))) float f32x4;
typedef __attribute__((ext_vector_type(4))) unsigned short u16x4;

#define BATCH 4
#define SEQ 2048
#define DMODEL 1024
#define DM 2048
#define NST 16
#define NH 32
#define MROWS (BATCH*SEQ)      // 8192
#define NCHUNK 32
#define CLEN (SEQ/NCHUNK)      // 64

__device__ __forceinline__ u16 f2b(float f){
  union { float f; unsigned u; } v; v.f = f;
  unsigned r = (v.u + 0x7fffu + ((v.u >> 16) & 1u)) >> 16;   // RNE
  return (u16)r;
}
__device__ __forceinline__ float b2f(u16 u){
  union { unsigned u; float f; } v; v.u = ((unsigned)u) << 16;
  return v.f;
}

// async global->LDS, 16B per lane; lptr must be wave-uniform [m97/m104]
__device__ __forceinline__ void async_ld16(const u16* g, u16* l){
  __builtin_amdgcn_global_load_lds(
      (const __attribute__((address_space(1))) void*)g,
      (__attribute__((address_space(3))) void*)l, 16, 0, 0);
}

// ---------------- f32 -> bf16 bulk convert (vectorized, exact grids) -------
__global__ __launch_bounds__(256) void cvt_bf16(const float* __restrict__ s,
                                                u16* __restrict__ d){
  int i = blockIdx.x*256 + threadIdx.x;
  float4 v = ((const float4*)s)[i];
  u16x4 o; o[0]=f2b(v.x); o[1]=f2b(v.y); o[2]=f2b(v.z); o[3]=f2b(v.w);
  ((u16x4*)d)[i] = o;
}

// ---------------- B/C projection + row L2-normalize ------------------------
__global__ __launch_bounds__(256) void bc_proj(
    const float* __restrict__ x,    // [MROWS, DMODEL] f32
    const float* __restrict__ Bw,   // [16, DMODEL]
    const float* __restrict__ Cw,   // [16, DMODEL]
    float* __restrict__ Bm, float* __restrict__ Cm)  // [MROWS,16]
{
  int wave = threadIdx.x >> 6;
  int lane = threadIdx.x & 63;
  int row  = blockIdx.x*4 + wave;
  int outn = lane & 15;
  int isC  = (lane >> 4) & 1;
  int khalf = lane >> 5;
  const float* wp = (isC ? Cw : Bw) + outn*DMODEL + khalf*(DMODEL/2);
  const float* xp = x + (size_t)row*DMODEL + khalf*(DMODEL/2);
  float acc = 0.f;
  for (int k = 0; k < DMODEL/2; k += 4){
    float4 xv = *(const float4*)&xp[k];
    float4 wv = *(const float4*)&wp[k];
    acc += xv.x*wv.x + xv.y*wv.y + xv.z*wv.z + xv.w*wv.w;
  }
  acc += __shfl_xor(acc, 32, 64);          // combine K halves
  float ss = acc*acc;                      // L2 over the 16-group
  ss += __shfl_xor(ss, 1, 64);
  ss += __shfl_xor(ss, 2, 64);
  ss += __shfl_xor(ss, 4, 64);
  ss += __shfl_xor(ss, 8, 64);
  float v = acc / fmaxf(sqrtf(ss), 1.0f);
  if (lane < 32){
    (isC ? Cm : Bm)[(size_t)row*NST + outn] = v;
  }
}

// ---------------- bf16 MFMA GEMM: C[M,N] = A[M,K] @ W[N,K]^T ---------------
// 128x128 tile, BK=32, async global_load_lds staging (m97 structure).
// LDS layout: unpadded [row][32] shorts (64 B rows) — required by
// global_load_lds lane-contiguity (wave lane L -> row L>>2, seg L&3).
// EPI: 2 = store f32 (final out)
//      3 = fused proj split: col<DM -> x_ssm bf16; col>=DM -> dt softplus f32
template<int EPI>
__global__ __launch_bounds__(256) void gemm_bt(
    const u16* __restrict__ A, const u16* __restrict__ W,
    float* __restrict__ Cf, u16* __restrict__ Cb,
    const float* __restrict__ bias, int N, int K)
{
  __shared__ u16 As[128*32];
  __shared__ u16 Ws[128*32];
  const int tid  = threadIdx.x;
  const int lane = tid & 63;
  const int wave = tid >> 6;
  const int qk = lane >> 4;     // k-quad: k = qk*8 + j
  const int rl = lane & 15;     // m/n within 16-tile
  const int wm = (wave >> 1) << 6;
  const int wn = (wave & 1) << 6;
  const int rowA0 = blockIdx.y * 128;
  const int rowW0 = blockIdx.x * 128;

  f32x4 acc[4][4];
#pragma unroll
  for (int mi=0;mi<4;mi++)
#pragma unroll
    for (int ni=0;ni<4;ni++)
      acc[mi][ni] = (f32x4){0.f,0.f,0.f,0.f};

  // async staging: wave stages rows [wave*32, wave*32+32) of both tiles.
  // lane L: row gr + (L>>2), shorts (L&3)*8..+8 -> lands at ldsbase + L*16B.
  const int gr0 = wave * 32;
  const u16* Ag = A + (size_t)(rowA0 + gr0 + (lane>>2))*K + ((lane&3)<<3);
  const u16* Wg = W + (size_t)(rowW0 + gr0 + (lane>>2))*K + ((lane&3)<<3);
  u16* AsD0 = &As[gr0*32];          // wave-uniform LDS dests
  u16* AsD1 = &As[(gr0+16)*32];
  u16* WsD0 = &Ws[gr0*32];
  u16* WsD1 = &Ws[(gr0+16)*32];
  const size_t rstep16 = (size_t)16*K;

  for (int k0 = 0; k0 < K; k0 += 32){
    __syncthreads();                       // prior ds_reads done before overwrite
    async_ld16(Ag + k0,           AsD0);
    async_ld16(Ag + rstep16 + k0, AsD1);
    async_ld16(Wg + k0,           WsD0);
    async_ld16(Wg + rstep16 + k0, WsD1);
    __syncthreads();                       // drains vmcnt (loads visible in LDS)
    s16x8 af[4], bfr[4];
#pragma unroll
    for (int mi=0;mi<4;mi++) af[mi]  = *(const s16x8*)&As[(wm + mi*16 + rl)*32 + qk*8];
#pragma unroll
    for (int ni=0;ni<4;ni++) bfr[ni] = *(const s16x8*)&Ws[(wn + ni*16 + rl)*32 + qk*8];
#pragma unroll
    for (int mi=0;mi<4;mi++)
#pragma unroll
      for (int ni=0;ni<4;ni++)
        acc[mi][ni] = __builtin_amdgcn_mfma_f32_16x16x32_bf16(af[mi], bfr[ni], acc[mi][ni], 0, 0, 0);
  }

  // C/D layout: col = lane&15, row = (lane>>4)*4 + reg   [m89/m91 verified]
  const int crow = rowA0 + wm + qk*4;
  const int ccol = rowW0 + wn + rl;
#pragma unroll
  for (int mi=0;mi<4;mi++){
#pragma unroll
    for (int ni=0;ni<4;ni++){
      const int col = ccol + ni*16;
#pragma unroll
      for (int r=0;r<4;r++){
        const int row = crow + mi*16 + r;
        float v = acc[mi][ni][r];
        if constexpr (EPI == 2){
          Cf[(size_t)row*N + col] = v;
        } else {   // EPI == 3: fused projection split (branch is wave-uniform)
          if (col < DM){
            Cb[(size_t)row*DM + col] = f2b(v);
          } else {
            int cc = col - DM;
            float t = v + bias[cc];
            t = fminf(fmaxf(t, -10.f), 5.f);
            float sp = (t > 0.f) ? (t + log1pf(__expf(-t))) : log1pf(__expf(t));
            sp = fminf(fmaxf(sp, 1e-4f), 0.1f);
            Cf[(size_t)row*DM + cc] = sp;
          }
        }
      }
    }
  }
}

// ---------------- selective scan: 3-pass chunked --------------------------
__global__ __launch_bounds__(256) void scan_pass1(
    const float* __restrict__ dtb, const u16* __restrict__ xbf,
    const float* __restrict__ Bm, const float* __restrict__ A_log,
    float* __restrict__ hbuf, float* __restrict__ sdtb)
{
  int tid = blockIdx.x*256 + threadIdx.x;   // (b*NCHUNK + c)*DM + d
  int d  = tid & (DM-1);
  int bc = tid >> 11;
  int c  = bc & (NCHUNK-1);
  int b  = bc >> 5;
  int head = d >> 6;                        // DM/NH = 64 channels per head
  float mA2[NST];
#pragma unroll
  for (int n=0;n<NST;n++)
    mA2[n] = -__expf(A_log[head*NST+n]) * 1.44269504088896341f;  // -A*log2(e)
  float h[NST];
#pragma unroll
  for (int n=0;n<NST;n++) h[n] = 0.f;
  float sdt = 0.f;
  int rowbase = b*SEQ + c*CLEN;
  for (int t=0;t<CLEN;t++){
    int row = rowbase + t;
    float dtv = dtb[(size_t)row*DM + d];
    float xv  = b2f(xbf[(size_t)row*DM + d]);
    sdt += dtv;
    float dtx = dtv*xv;
    const float4* bp = (const float4*)&Bm[(size_t)row*NST];
    float4 b0=bp[0],b1=bp[1],b2=bp[2],b3=bp[3];
    float bb[NST] = {b0.x,b0.y,b0.z,b0.w, b1.x,b1.y,b1.z,b1.w,
                     b2.x,b2.y,b2.z,b2.w, b3.x,b3.y,b3.z,b3.w};
#pragma unroll
    for (int n=0;n<NST;n++)
      h[n] = exp2f(dtv*mA2[n])*h[n] + dtx*bb[n];
  }
  float* hp = &hbuf[((size_t)(b*DM + d)*NCHUNK + c)*NST];
#pragma unroll
  for (int n=0;n<NST;n++) hp[n] = h[n];
  sdtb[(size_t)(b*DM + d)*NCHUNK + c] = sdt;
}

__global__ __launch_bounds__(256) void scan_pass2(
    float* __restrict__ hbuf, const float* __restrict__ sdtb,
    const float* __restrict__ A_log)
{
  int tid = blockIdx.x*256 + threadIdx.x;   // b*DM*NST
  int n  = tid & (NST-1);
  int bd = tid >> 4;
  int d  = bd & (DM-1);
  int head = d >> 6;
  float mA2 = -__expf(A_log[head*NST+n]) * 1.44269504088896341f;
  float hrun = 0.f;
  size_t base = (size_t)bd*NCHUNK*NST + n;
  size_t sbase = (size_t)bd*NCHUNK;
  for (int c=0;c<NCHUNK;c++){
    float ho = hbuf[base + c*NST];
    float dp = exp2f(mA2 * sdtb[sbase + c]);   // exact chunk decay product
    hbuf[base + c*NST] = hrun;                  // h_in for chunk c
    hrun = dp*hrun + ho;
  }
}

__global__ __launch_bounds__(256) void scan_pass3(
    const float* __restrict__ dtb, const u16* __restrict__ xbf,
    const float* __restrict__ Bm, const float* __restrict__ Cm,
    const float* __restrict__ A_log, const float* __restrict__ Dvec,
    const float* __restrict__ hbuf, u16* __restrict__ ybf)
{
  int tid = blockIdx.x*256 + threadIdx.x;
  int d  = tid & (DM-1);
  int bc = tid >> 11;
  int c  = bc & (NCHUNK-1);
  int b  = bc >> 5;
  int head = d >> 6;
  float mA2[NST];
#pragma unroll
  for (int n=0;n<NST;n++)
    mA2[n] = -__expf(A_log[head*NST+n]) * 1.44269504088896341f;
  float h[NST];
  const float* hp = &hbuf[((size_t)(b*DM + d)*NCHUNK + c)*NST];
#pragma unroll
  for (int n=0;n<NST;n++) h[n] = hp[n];
  float Dv = Dvec[d];
  int rowbase = b*SEQ + c*CLEN;
  for (int t=0;t<CLEN;t++){
    int row = rowbase + t;
    float dtv = dtb[(size_t)row*DM + d];
    float xv  = b2f(xbf[(size_t)row*DM + d]);
    float dtx = dtv*xv;
    const float4* bp = (const float4*)&Bm[(size_t)row*NST];
    const float4* cp = (const float4*)&Cm[(size_t)row*NST];
    float4 b0=bp[0],b1=bp[1],b2=bp[2],b3=bp[3];
    float4 c0=cp[0],c1=cp[1],c2=cp[2],c3=cp[3];
    float bb[NST] = {b0.x,b0.y,b0.z,b0.w, b1.x,b1.y,b1.z,b1.w,
                     b2.x,b2.y,b2.z,b2.w, b3.x,b3.y,b3.z,b3.w};
    float cc[NST] = {c0.x,c0.y,c0.z,c0.w, c1.x,c1.y,c1.z,c1.w,
                     c2.x,c2.y,c2.z,c2.w, c3.x,c3.y,c3.z,c3.w};
    float y = 0.f;
#pragma unroll
    for (int n=0;n<NST;n++){
      h[n] = exp2f(dtv*mA2[n])*h[n] + dtx*bb[n];
      y += h[n]*cc[n];
    }
    y += xv*Dv;
    ybf[(size_t)row*DM + d] = f2b(y);
  }
}

// ---------------------------------------------------------------------------
extern "C" void kernel_launch(void* const* d_in, const int* in_sizes, int n_in,
                              void* d_out, int out_size, void* d_ws, size_t ws_size,
                              hipStream_t stream)
{
  (void)in_sizes; (void)n_in; (void)out_size; (void)ws_size;
  const float* x_norm    = (const float*)d_in[0];
  const float* x_proj_w  = (const float*)d_in[1];
  const float* dt_proj_w = (const float*)d_in[2];
  const float* dt_proj_b = (const float*)d_in[3];
  const float* B_proj_w  = (const float*)d_in[4];
  const float* C_proj_w  = (const float*)d_in[5];
  const float* A_log     = (const float*)d_in[6];
  const float* Dvec      = (const float*)d_in[7];
  const float* out_w     = (const float*)d_in[8];
  float* out = (float*)d_out;
  char* ws = (char*)d_ws;

  size_t off = 0;
  auto take = [&](size_t bytes)->void*{
    void* p = ws + off; off += (bytes + 255) & ~(size_t)255; return p;
  };
  u16*   xb     = (u16*)  take((size_t)MROWS*DMODEL*2);    // x_norm bf16
  u16*   wstack = (u16*)  take((size_t)2*DM*DMODEL*2);     // [x_proj_w; dt_proj_w] bf16
  u16*   woutb  = (u16*)  take((size_t)DM*DM*2);           // out_proj_w bf16
  u16*   xssmb  = (u16*)  take((size_t)MROWS*DM*2);        // x_ssm bf16
  float* dtf    = (float*)take((size_t)MROWS*DM*4);        // dt f32
  float* Bmb    = (float*)take((size_t)MROWS*NST*4);
  float* Cmb    = (float*)take((size_t)MROWS*NST*4);
  float* hbuf   = (float*)take((size_t)BATCH*DM*NCHUNK*NST*4);
  float* sdtb   = (float*)take((size_t)BATCH*DM*NCHUNK*4);
  u16*   ybf    = (u16*)  take((size_t)MROWS*DM*2);        // y bf16

  cvt_bf16<<<MROWS*DMODEL/1024, 256, 0, stream>>>(x_norm, xb);
  cvt_bf16<<<DM*DMODEL/1024,    256, 0, stream>>>(x_proj_w,  wstack);
  cvt_bf16<<<DM*DMODEL/1024,    256, 0, stream>>>(dt_proj_w, wstack + (size_t)DM*DMODEL);
  cvt_bf16<<<DM*DM/1024,        256, 0, stream>>>(out_w, woutb);
  bc_proj<<<MROWS/4, 256, 0, stream>>>(x_norm, B_proj_w, C_proj_w, Bmb, Cmb);
  // fused x_ssm + dt projection: N = 2*DM = 4096, K = DMODEL
  gemm_bt<3><<<dim3(2*DM/128, MROWS/128), 256, 0, stream>>>(xb, wstack, dtf, xssmb, dt_proj_b, 2*DM, DMODEL);
  scan_pass1<<<BATCH*NCHUNK*DM/256, 256, 0, stream>>>(dtf, xssmb, Bmb, A_log, hbuf, sdtb);
  scan_pass2<<<BATCH*DM*NST/256,    256, 0, stream>>>(hbuf, sdtb, A_log);
  scan_pass3<<<BATCH*NCHUNK*DM/256, 256, 0, stream>>>(dtf, xssmb, Bmb, Cmb, A_log, Dvec, hbuf, ybf);
  gemm_bt<2><<<dim3(DM/128, MROWS/128), 256, 0, stream>>>(ybf, woutb, out, nullptr, nullptr, DM, DM);
}

// Round 3
// 694.084 us; speedup vs baseline: 1.3141x; 1.1829x over previous
//
#include <hip/hip_runtime.h>

typedef unsigned short u16;
typedef __attribute__((ext_vector_type(8))) short s16x8;
typedef __attribute__((ext_vector_type(4))) float f32x4;
typedef __attribute__((ext_vector_type(4))) unsigned short u16x4;

#define BATCH 4
#define SEQ 2048
#define DMODEL 1024
#define DM 2048
#define NST 16
#define NH 32
#define MROWS (BATCH*SEQ)      // 8192
#define NCHUNK 32
#define CLEN (SEQ/NCHUNK)      // 64

__device__ __forceinline__ u16 f2b(float f){
  union { float f; unsigned u; } v; v.f = f;
  unsigned r = (v.u + 0x7fffu + ((v.u >> 16) & 1u)) >> 16;   // RNE
  return (u16)r;
}
__device__ __forceinline__ float b2f(u16 u){
  union { unsigned u; float f; } v; v.u = ((unsigned)u) << 16;
  return v.f;
}

// async global->LDS, 16B per lane; lptr must be wave-uniform [m97/m104]
__device__ __forceinline__ void async_ld16(const u16* g, u16* l){
  __builtin_amdgcn_global_load_lds(
      (const __attribute__((address_space(1))) void*)g,
      (__attribute__((address_space(3))) void*)l, 16, 0, 0);
}

// ---------------- f32 -> bf16 bulk convert (vectorized, exact grids) -------
__global__ __launch_bounds__(256) void cvt_bf16(const float* __restrict__ s,
                                                u16* __restrict__ d){
  int i = blockIdx.x*256 + threadIdx.x;
  float4 v = ((const float4*)s)[i];
  u16x4 o; o[0]=f2b(v.x); o[1]=f2b(v.y); o[2]=f2b(v.z); o[3]=f2b(v.w);
  ((u16x4*)d)[i] = o;
}

// ---------------- B/C projection + row L2-normalize ------------------------
__global__ __launch_bounds__(256) void bc_proj(
    const float* __restrict__ x,    // [MROWS, DMODEL] f32
    const float* __restrict__ Bw,   // [16, DMODEL]
    const float* __restrict__ Cw,   // [16, DMODEL]
    float* __restrict__ Bm, float* __restrict__ Cm)  // [MROWS,16]
{
  int wave = threadIdx.x >> 6;
  int lane = threadIdx.x & 63;
  int row  = blockIdx.x*4 + wave;
  int outn = lane & 15;
  int isC  = (lane >> 4) & 1;
  int khalf = lane >> 5;
  const float* wp = (isC ? Cw : Bw) + outn*DMODEL + khalf*(DMODEL/2);
  const float* xp = x + (size_t)row*DMODEL + khalf*(DMODEL/2);
  float acc = 0.f;
  for (int k = 0; k < DMODEL/2; k += 4){
    float4 xv = *(const float4*)&xp[k];
    float4 wv = *(const float4*)&wp[k];
    acc += xv.x*wv.x + xv.y*wv.y + xv.z*wv.z + xv.w*wv.w;
  }
  acc += __shfl_xor(acc, 32, 64);          // combine K halves
  float ss = acc*acc;                      // L2 over the 16-group
  ss += __shfl_xor(ss, 1, 64);
  ss += __shfl_xor(ss, 2, 64);
  ss += __shfl_xor(ss, 4, 64);
  ss += __shfl_xor(ss, 8, 64);
  float v = acc / fmaxf(sqrtf(ss), 1.0f);
  if (lane < 32){
    (isC ? Cm : Bm)[(size_t)row*NST + outn] = v;
  }
}

// ---------------- bf16 MFMA GEMM: C[M,N] = A[M,K] @ W[N,K]^T ---------------
// 128x128 tile, BK=32, DOUBLE-BUFFERED async global_load_lds staging.
// LDS: unpadded [row][32] shorts with XOR-swizzled 16B k-segments:
//   phys_seg(row, logical_seg q) = q ^ ((row>>1)&3)
// -> every 8-lane ds_read_b128 phase covers all 32 banks (conflict-free).
// Staging lane L covers row gr0+(L>>2); its LDS slot (seg L&3) must hold
// logical seg (L&3)^(((gr0+(L>>2))>>1)&3) = (L&3)^((L>>3)&3)  (gr0 mult of 32).
// EPI: 2 = store f32 (final out)
//      3 = fused proj split: col<DM -> x_ssm bf16; col>=DM -> dt bf16 (cheap
//          softplus: clip(softplus(clip(t)))==clamp(log1p(e^t)) with t
//          pre-clamped to [-9.22,-2.2521684], e^t<=0.1052 -> 4-term poly)
template<int EPI>
__global__ __launch_bounds__(256) void gemm_bt(
    const u16* __restrict__ A, const u16* __restrict__ W,
    float* __restrict__ Cf, u16* __restrict__ Cb, u16* __restrict__ Cb2,
    const float* __restrict__ bias, int N, int K)
{
  __shared__ u16 As[2][128*32];
  __shared__ u16 Ws[2][128*32];
  const int tid  = threadIdx.x;
  const int lane = tid & 63;
  const int wave = tid >> 6;
  const int qk = lane >> 4;     // k-quad: k = qk*8 + j
  const int rl = lane & 15;     // m/n within 16-tile
  const int qs = qk ^ ((rl >> 1) & 3);   // swizzled k-seg for fragment reads
  const int wm = (wave >> 1) << 6;
  const int wn = (wave & 1) << 6;
  const int rowA0 = blockIdx.y * 128;
  const int rowW0 = blockIdx.x * 128;

  f32x4 acc[4][4];
#pragma unroll
  for (int mi=0;mi<4;mi++)
#pragma unroll
    for (int ni=0;ni<4;ni++)
      acc[mi][ni] = (f32x4){0.f,0.f,0.f,0.f};

  const int gr0 = wave * 32;
  const int slog = (lane & 3) ^ ((lane >> 3) & 3);     // swizzled global seg
  const u16* Ag = A + (size_t)(rowA0 + gr0 + (lane>>2))*K + slog*8;
  const u16* Wg = W + (size_t)(rowW0 + gr0 + (lane>>2))*K + slog*8;
  const size_t rstep16 = (size_t)16*K;   // row+16: (row>>1)&3 unchanged -> same slog

  u16* AsD0[2] = { &As[0][gr0*32], &As[1][gr0*32] };
  u16* AsD1[2] = { &As[0][(gr0+16)*32], &As[1][(gr0+16)*32] };
  u16* WsD0[2] = { &Ws[0][gr0*32], &Ws[1][gr0*32] };
  u16* WsD1[2] = { &Ws[0][(gr0+16)*32], &Ws[1][(gr0+16)*32] };

  // prologue: stage k-step 0 into buf 0
  async_ld16(Ag,           AsD0[0]);
  async_ld16(Ag + rstep16, AsD1[0]);
  async_ld16(Wg,           WsD0[0]);
  async_ld16(Wg + rstep16, WsD1[0]);

  const int S = K >> 5;
  for (int s = 0; s < S; s++){
    const int cur = s & 1;
    __syncthreads();   // drains own async loads (buf cur) + everyone done
                       // reading buf cur^1 from step s-1 -> safe to refill it
    if (s + 1 < S){
      const int k1 = (s+1) << 5;
      async_ld16(Ag + k1,           AsD0[cur^1]);
      async_ld16(Ag + rstep16 + k1, AsD1[cur^1]);
      async_ld16(Wg + k1,           WsD0[cur^1]);
      async_ld16(Wg + rstep16 + k1, WsD1[cur^1]);
    }
    s16x8 af[4], bfr[4];
#pragma unroll
    for (int mi=0;mi<4;mi++) af[mi]  = *(const s16x8*)&As[cur][(wm + mi*16 + rl)*32 + qs*8];
#pragma unroll
    for (int ni=0;ni<4;ni++) bfr[ni] = *(const s16x8*)&Ws[cur][(wn + ni*16 + rl)*32 + qs*8];
#pragma unroll
    for (int mi=0;mi<4;mi++)
#pragma unroll
      for (int ni=0;ni<4;ni++)
        acc[mi][ni] = __builtin_amdgcn_mfma_f32_16x16x32_bf16(af[mi], bfr[ni], acc[mi][ni], 0, 0, 0);
  }

  // C/D layout: col = lane&15, row = (lane>>4)*4 + reg   [m89/m91 verified]
  const int crow = rowA0 + wm + qk*4;
  const int ccol = rowW0 + wn + rl;
#pragma unroll
  for (int mi=0;mi<4;mi++){
#pragma unroll
    for (int ni=0;ni<4;ni++){
      const int col = ccol + ni*16;
#pragma unroll
      for (int r=0;r<4;r++){
        const int row = crow + mi*16 + r;
        float v = acc[mi][ni][r];
        if constexpr (EPI == 2){
          Cf[(size_t)row*N + col] = v;
        } else {   // EPI == 3: fused projection split (branch is wave-uniform)
          if (col < DM){
            Cb[(size_t)row*DM + col] = f2b(v);
          } else {
            int cc = col - DM;
            float t = v + bias[cc];
            t = fminf(fmaxf(t, -9.22f), -2.2521684f);
            float x = __expf(t);                       // <= 0.10517
            float sp = x*(1.f - x*(0.5f - x*(0.33333333f - x*0.25f)));
            sp = fminf(fmaxf(sp, 1e-4f), 0.1f);
            Cb2[(size_t)row*DM + cc] = f2b(sp);
          }
        }
      }
    }
  }
}

// ---------------- selective scan: 3-pass chunked --------------------------
__global__ __launch_bounds__(256) void scan_pass1(
    const u16* __restrict__ dtb, const u16* __restrict__ xbf,
    const float* __restrict__ Bm, const float* __restrict__ A_log,
    float* __restrict__ hbuf, float* __restrict__ sdtb)
{
  int tid = blockIdx.x*256 + threadIdx.x;   // (b*NCHUNK + c)*DM + d
  int d  = tid & (DM-1);
  int bc = tid >> 11;
  int c  = bc & (NCHUNK-1);
  int b  = bc >> 5;
  int head = d >> 6;                        // DM/NH = 64 channels per head
  float mA2[NST];
#pragma unroll
  for (int n=0;n<NST;n++)
    mA2[n] = -__expf(A_log[head*NST+n]) * 1.44269504088896341f;  // -A*log2(e)
  float h[NST];
#pragma unroll
  for (int n=0;n<NST;n++) h[n] = 0.f;
  float sdt = 0.f;
  int rowbase = b*SEQ + c*CLEN;
  for (int t=0;t<CLEN;t++){
    int row = rowbase + t;
    float dtv = b2f(dtb[(size_t)row*DM + d]);
    float xv  = b2f(xbf[(size_t)row*DM + d]);
    sdt += dtv;
    float dtx = dtv*xv;
    const float4* bp = (const float4*)&Bm[(size_t)row*NST];
    float4 b0=bp[0],b1=bp[1],b2=bp[2],b3=bp[3];
    float bb[NST] = {b0.x,b0.y,b0.z,b0.w, b1.x,b1.y,b1.z,b1.w,
                     b2.x,b2.y,b2.z,b2.w, b3.x,b3.y,b3.z,b3.w};
#pragma unroll
    for (int n=0;n<NST;n++)
      h[n] = exp2f(dtv*mA2[n])*h[n] + dtx*bb[n];
  }
  float* hp = &hbuf[((size_t)(b*DM + d)*NCHUNK + c)*NST];
#pragma unroll
  for (int n=0;n<NST;n++) hp[n] = h[n];
  sdtb[(size_t)(b*DM + d)*NCHUNK + c] = sdt;
}

__global__ __launch_bounds__(256) void scan_pass2(
    float* __restrict__ hbuf, const float* __restrict__ sdtb,
    const float* __restrict__ A_log)
{
  int tid = blockIdx.x*256 + threadIdx.x;   // b*DM*NST
  int n  = tid & (NST-1);
  int bd = tid >> 4;
  int d  = bd & (DM-1);
  int head = d >> 6;
  float mA2 = -__expf(A_log[head*NST+n]) * 1.44269504088896341f;
  float hrun = 0.f;
  size_t base = (size_t)bd*NCHUNK*NST + n;
  size_t sbase = (size_t)bd*NCHUNK;
  for (int c=0;c<NCHUNK;c++){
    float ho = hbuf[base + c*NST];
    float dp = exp2f(mA2 * sdtb[sbase + c]);   // exact chunk decay product
    hbuf[base + c*NST] = hrun;                  // h_in for chunk c
    hrun = dp*hrun + ho;
  }
}

__global__ __launch_bounds__(256) void scan_pass3(
    const u16* __restrict__ dtb, const u16* __restrict__ xbf,
    const float* __restrict__ Bm, const float* __restrict__ Cm,
    const float* __restrict__ A_log, const float* __restrict__ Dvec,
    const float* __restrict__ hbuf, u16* __restrict__ ybf)
{
  int tid = blockIdx.x*256 + threadIdx.x;
  int d  = tid & (DM-1);
  int bc = tid >> 11;
  int c  = bc & (NCHUNK-1);
  int b  = bc >> 5;
  int head = d >> 6;
  float mA2[NST];
#pragma unroll
  for (int n=0;n<NST;n++)
    mA2[n] = -__expf(A_log[head*NST+n]) * 1.44269504088896341f;
  float h[NST];
  const float* hp = &hbuf[((size_t)(b*DM + d)*NCHUNK + c)*NST];
#pragma unroll
  for (int n=0;n<NST;n++) h[n] = hp[n];
  float Dv = Dvec[d];
  int rowbase = b*SEQ + c*CLEN;
  for (int t=0;t<CLEN;t++){
    int row = rowbase + t;
    float dtv = b2f(dtb[(size_t)row*DM + d]);
    float xv  = b2f(xbf[(size_t)row*DM + d]);
    float dtx = dtv*xv;
    const float4* bp = (const float4*)&Bm[(size_t)row*NST];
    const float4* cp = (const float4*)&Cm[(size_t)row*NST];
    float4 b0=bp[0],b1=bp[1],b2=bp[2],b3=bp[3];
    float4 c0=cp[0],c1=cp[1],c2=cp[2],c3=cp[3];
    float bb[NST] = {b0.x,b0.y,b0.z,b0.w, b1.x,b1.y,b1.z,b1.w,
                     b2.x,b2.y,b2.z,b2.w, b3.x,b3.y,b3.z,b3.w};
    float cc[NST] = {c0.x,c0.y,c0.z,c0.w, c1.x,c1.y,c1.z,c1.w,
                     c2.x,c2.y,c2.z,c2.w, c3.x,c3.y,c3.z,c3.w};
    float y = 0.f;
#pragma unroll
    for (int n=0;n<NST;n++){
      h[n] = exp2f(dtv*mA2[n])*h[n] + dtx*bb[n];
      y += h[n]*cc[n];
    }
    y += xv*Dv;
    ybf[(size_t)row*DM + d] = f2b(y);
  }
}

// ---------------------------------------------------------------------------
extern "C" void kernel_launch(void* const* d_in, const int* in_sizes, int n_in,
                              void* d_out, int out_size, void* d_ws, size_t ws_size,
                              hipStream_t stream)
{
  (void)in_sizes; (void)n_in; (void)out_size; (void)ws_size;
  const float* x_norm    = (const float*)d_in[0];
  const float* x_proj_w  = (const float*)d_in[1];
  const float* dt_proj_w = (const float*)d_in[2];
  const float* dt_proj_b = (const float*)d_in[3];
  const float* B_proj_w  = (const float*)d_in[4];
  const float* C_proj_w  = (const float*)d_in[5];
  const float* A_log     = (const float*)d_in[6];
  const float* Dvec      = (const float*)d_in[7];
  const float* out_w     = (const float*)d_in[8];
  float* out = (float*)d_out;
  char* ws = (char*)d_ws;

  size_t off = 0;
  auto take = [&](size_t bytes)->void*{
    void* p = ws + off; off += (bytes + 255) & ~(size_t)255; return p;
  };
  u16*   xb     = (u16*)  take((size_t)MROWS*DMODEL*2);    // x_norm bf16
  u16*   wstack = (u16*)  take((size_t)2*DM*DMODEL*2);     // [x_proj_w; dt_proj_w] bf16
  u16*   woutb  = (u16*)  take((size_t)DM*DM*2);           // out_proj_w bf16
  u16*   xssmb  = (u16*)  take((size_t)MROWS*DM*2);        // x_ssm bf16
  u16*   dtb    = (u16*)  take((size_t)MROWS*DM*2);        // dt bf16
  float* Bmb    = (float*)take((size_t)MROWS*NST*4);
  float* Cmb    = (float*)take((size_t)MROWS*NST*4);
  float* hbuf   = (float*)take((size_t)BATCH*DM*NCHUNK*NST*4);
  float* sdtb   = (float*)take((size_t)BATCH*DM*NCHUNK*4);
  u16*   ybf    = (u16*)  take((size_t)MROWS*DM*2);        // y bf16

  cvt_bf16<<<MROWS*DMODEL/1024, 256, 0, stream>>>(x_norm, xb);
  cvt_bf16<<<DM*DMODEL/1024,    256, 0, stream>>>(x_proj_w,  wstack);
  cvt_bf16<<<DM*DMODEL/1024,    256, 0, stream>>>(dt_proj_w, wstack + (size_t)DM*DMODEL);
  cvt_bf16<<<DM*DM/1024,        256, 0, stream>>>(out_w, woutb);
  bc_proj<<<MROWS/4, 256, 0, stream>>>(x_norm, B_proj_w, C_proj_w, Bmb, Cmb);
  // fused x_ssm + dt projection: N = 2*DM = 4096, K = DMODEL
  gemm_bt<3><<<dim3(2*DM/128, MROWS/128), 256, 0, stream>>>(xb, wstack, nullptr, xssmb, dtb, dt_proj_b, 2*DM, DMODEL);
  scan_pass1<<<BATCH*NCHUNK*DM/256, 256, 0, stream>>>(dtb, xssmb, Bmb, A_log, hbuf, sdtb);
  scan_pass2<<<BATCH*DM*NST/256,    256, 0, stream>>>(hbuf, sdtb, A_log);
  scan_pass3<<<BATCH*NCHUNK*DM/256, 256, 0, stream>>>(dtb, xssmb, Bmb, Cmb, A_log, Dvec, hbuf, ybf);
  gemm_bt<2><<<dim3(DM/128, MROWS/128), 256, 0, stream>>>(ybf, woutb, out, nullptr, nullptr, nullptr, DM, DM);
}

// Round 4
// 563.461 us; speedup vs baseline: 1.6188x; 1.2318x over previous
//
#include <hip/hip_runtime.h>

typedef unsigned short u16;
typedef __attribute__((ext_vector_type(8))) short s16x8;
typedef __attribute__((ext_vector_type(4))) float f32x4;
typedef __attribute__((ext_vector_type(4))) unsigned short u16x4;

#define BATCH 4
#define SEQ 2048
#define DMODEL 1024
#define DM 2048
#define NST 16
#define NH 32
#define MROWS (BATCH*SEQ)      // 8192
#define NCHUNK 32
#define CLEN (SEQ/NCHUNK)      // 64
#define NSTACK (2*DM + 128)    // 4224 = 33 tiles of 128; cols 4096..4127 = B,C

__device__ __forceinline__ u16 f2b(float f){
  union { float f; unsigned u; } v; v.f = f;
  unsigned r = (v.u + 0x7fffu + ((v.u >> 16) & 1u)) >> 16;   // RNE
  return (u16)r;
}
__device__ __forceinline__ float b2f(u16 u){
  union { unsigned u; float f; } v; v.u = ((unsigned)u) << 16;
  return v.f;
}

// async global->LDS, 16B per lane; lptr must be wave-uniform [m97/m104]
__device__ __forceinline__ void async_ld16(const u16* g, u16* l){
  __builtin_amdgcn_global_load_lds(
      (const __attribute__((address_space(1))) void*)g,
      (__attribute__((address_space(3))) void*)l, 16, 0, 0);
}

// ---------------- f32 -> bf16 bulk convert (vectorized, exact grids) -------
__global__ __launch_bounds__(256) void cvt_bf16(const float* __restrict__ s,
                                                u16* __restrict__ d){
  int i = blockIdx.x*256 + threadIdx.x;
  float4 v = ((const float4*)s)[i];
  u16x4 o; o[0]=f2b(v.x); o[1]=f2b(v.y); o[2]=f2b(v.z); o[3]=f2b(v.w);
  ((u16x4*)d)[i] = o;
}

// ---------------- B/C row L2-normalize (proj computed in main GEMM) --------
// raw: [MROWS, 32] f32 (B in cols 0..15, C in 16..31)
__global__ __launch_bounds__(256) void bc_norm(const float* __restrict__ raw,
                                               float* __restrict__ Bm,
                                               float* __restrict__ Cm){
  int t = blockIdx.x*256 + threadIdx.x;    // row*32 + c32
  int c32 = t & 31;
  int row = t >> 5;
  float v = raw[t];
  float ss = v*v;                           // reduce over the 16-group
  ss += __shfl_xor(ss, 1, 64);
  ss += __shfl_xor(ss, 2, 64);
  ss += __shfl_xor(ss, 4, 64);
  ss += __shfl_xor(ss, 8, 64);
  float o = v / fmaxf(sqrtf(ss), 1.0f);
  int outn = c32 & 15;
  if (c32 < 16) Bm[(size_t)row*NST + outn] = o;
  else          Cm[(size_t)row*NST + outn] = o;
}

// ---------------- bf16 MFMA GEMM: C[M,N] = A[M,K] @ W[N,K]^T ---------------
// 128x128 tile, BK=32, DOUBLE-BUFFERED async global_load_lds staging.
// LDS: unpadded [row][32] shorts with XOR-swizzled 16B k-segments:
//   phys_seg(row, logical_seg q) = q ^ ((row>>1)&3)   -> conflict-free b128.
// EPI: 2 = store f32 (final out)
//      3 = fused proj split over col: [0,DM) x_ssm bf16; [DM,2DM) dt bf16
//          (cheap exact softplus); [2DM,2DM+32) raw B/C f32; >= skip (pad)
template<int EPI>
__global__ __launch_bounds__(256) void gemm_bt(
    const u16* __restrict__ A, const u16* __restrict__ W,
    float* __restrict__ Cf, u16* __restrict__ Cb, u16* __restrict__ Cb2,
    const float* __restrict__ bias, int N, int K)
{
  __shared__ u16 As[2][128*32];
  __shared__ u16 Ws[2][128*32];
  const int tid  = threadIdx.x;
  const int lane = tid & 63;
  const int wave = tid >> 6;
  const int qk = lane >> 4;     // k-quad: k = qk*8 + j
  const int rl = lane & 15;     // m/n within 16-tile
  const int qs = qk ^ ((rl >> 1) & 3);   // swizzled k-seg for fragment reads
  const int wm = (wave >> 1) << 6;
  const int wn = (wave & 1) << 6;
  const int rowA0 = blockIdx.y * 128;
  const int rowW0 = blockIdx.x * 128;

  f32x4 acc[4][4];
#pragma unroll
  for (int mi=0;mi<4;mi++)
#pragma unroll
    for (int ni=0;ni<4;ni++)
      acc[mi][ni] = (f32x4){0.f,0.f,0.f,0.f};

  const int gr0 = wave * 32;
  const int slog = (lane & 3) ^ ((lane >> 3) & 3);     // swizzled global seg
  const u16* Ag = A + (size_t)(rowA0 + gr0 + (lane>>2))*K + slog*8;
  const u16* Wg = W + (size_t)(rowW0 + gr0 + (lane>>2))*K + slog*8;
  const size_t rstep16 = (size_t)16*K;   // row+16: (row>>1)&3 unchanged -> same slog

  u16* AsD0[2] = { &As[0][gr0*32], &As[1][gr0*32] };
  u16* AsD1[2] = { &As[0][(gr0+16)*32], &As[1][(gr0+16)*32] };
  u16* WsD0[2] = { &Ws[0][gr0*32], &Ws[1][gr0*32] };
  u16* WsD1[2] = { &Ws[0][(gr0+16)*32], &Ws[1][(gr0+16)*32] };

  // prologue: stage k-step 0 into buf 0
  async_ld16(Ag,           AsD0[0]);
  async_ld16(Ag + rstep16, AsD1[0]);
  async_ld16(Wg,           WsD0[0]);
  async_ld16(Wg + rstep16, WsD1[0]);

  const int S = K >> 5;
  for (int s = 0; s < S; s++){
    const int cur = s & 1;
    __syncthreads();   // drains own async loads (buf cur) + everyone done
                       // reading buf cur^1 from step s-1 -> safe to refill it
    if (s + 1 < S){
      const int k1 = (s+1) << 5;
      async_ld16(Ag + k1,           AsD0[cur^1]);
      async_ld16(Ag + rstep16 + k1, AsD1[cur^1]);
      async_ld16(Wg + k1,           WsD0[cur^1]);
      async_ld16(Wg + rstep16 + k1, WsD1[cur^1]);
    }
    s16x8 af[4], bfr[4];
#pragma unroll
    for (int mi=0;mi<4;mi++) af[mi]  = *(const s16x8*)&As[cur][(wm + mi*16 + rl)*32 + qs*8];
#pragma unroll
    for (int ni=0;ni<4;ni++) bfr[ni] = *(const s16x8*)&Ws[cur][(wn + ni*16 + rl)*32 + qs*8];
#pragma unroll
    for (int mi=0;mi<4;mi++)
#pragma unroll
      for (int ni=0;ni<4;ni++)
        acc[mi][ni] = __builtin_amdgcn_mfma_f32_16x16x32_bf16(af[mi], bfr[ni], acc[mi][ni], 0, 0, 0);
  }

  // C/D layout: col = lane&15, row = (lane>>4)*4 + reg   [m89/m91 verified]
  const int crow = rowA0 + wm + qk*4;
  const int ccol = rowW0 + wn + rl;
#pragma unroll
  for (int mi=0;mi<4;mi++){
#pragma unroll
    for (int ni=0;ni<4;ni++){
      const int col = ccol + ni*16;
#pragma unroll
      for (int r=0;r<4;r++){
        const int row = crow + mi*16 + r;
        float v = acc[mi][ni][r];
        if constexpr (EPI == 2){
          Cf[(size_t)row*N + col] = v;
        } else {   // EPI == 3: fused projection split (wave-uniform per ni)
          if (col < DM){
            Cb[(size_t)row*DM + col] = f2b(v);
          } else if (col < 2*DM){
            int cc = col - DM;
            float t = v + bias[cc];
            t = fminf(fmaxf(t, -9.22f), -2.2521684f);
            float x = __expf(t);                       // <= 0.10517
            float sp = x*(1.f - x*(0.5f - x*(0.33333333f - x*0.25f)));
            sp = fminf(fmaxf(sp, 1e-4f), 0.1f);
            Cb2[(size_t)row*DM + cc] = f2b(sp);
          } else if (col < 2*DM + 32){
            Cf[(size_t)row*32 + (col - 2*DM)] = v;     // raw B/C
          }
          // else: padding columns (garbage weights) — never stored
        }
      }
    }
  }
}

// ---------------- selective scan: 3-pass chunked --------------------------
__global__ __launch_bounds__(256) void scan_pass1(
    const u16* __restrict__ dtb, const u16* __restrict__ xbf,
    const float* __restrict__ Bm, const float* __restrict__ A_log,
    float* __restrict__ hbuf, float* __restrict__ sdtb)
{
  int tid = blockIdx.x*256 + threadIdx.x;   // (b*NCHUNK + c)*DM + d
  int d  = tid & (DM-1);
  int bc = tid >> 11;
  int c  = bc & (NCHUNK-1);
  int b  = bc >> 5;
  int head = d >> 6;                        // DM/NH = 64 channels per head
  float mA2[NST];
#pragma unroll
  for (int n=0;n<NST;n++)
    mA2[n] = -__expf(A_log[head*NST+n]) * 1.44269504088896341f;  // -A*log2(e)
  float h[NST];
#pragma unroll
  for (int n=0;n<NST;n++) h[n] = 0.f;
  float sdt = 0.f;
  int rowbase = b*SEQ + c*CLEN;
  for (int t=0;t<CLEN;t++){
    int row = rowbase + t;
    float dtv = b2f(dtb[(size_t)row*DM + d]);
    float xv  = b2f(xbf[(size_t)row*DM + d]);
    sdt += dtv;
    float dtx = dtv*xv;
    const float4* bp = (const float4*)&Bm[(size_t)row*NST];
    float4 b0=bp[0],b1=bp[1],b2=bp[2],b3=bp[3];
    float bb[NST] = {b0.x,b0.y,b0.z,b0.w, b1.x,b1.y,b1.z,b1.w,
                     b2.x,b2.y,b2.z,b2.w, b3.x,b3.y,b3.z,b3.w};
#pragma unroll
    for (int n=0;n<NST;n++)
      h[n] = exp2f(dtv*mA2[n])*h[n] + dtx*bb[n];
  }
  float* hp = &hbuf[((size_t)(b*DM + d)*NCHUNK + c)*NST];
#pragma unroll
  for (int n=0;n<NST;n++) hp[n] = h[n];
  sdtb[(size_t)(b*DM + d)*NCHUNK + c] = sdt;
}

__global__ __launch_bounds__(256) void scan_pass2(
    float* __restrict__ hbuf, const float* __restrict__ sdtb,
    const float* __restrict__ A_log)
{
  int tid = blockIdx.x*256 + threadIdx.x;   // b*DM*NST
  int n  = tid & (NST-1);
  int bd = tid >> 4;
  int d  = bd & (DM-1);
  int head = d >> 6;
  float mA2 = -__expf(A_log[head*NST+n]) * 1.44269504088896341f;
  float hrun = 0.f;
  size_t base = (size_t)bd*NCHUNK*NST + n;
  size_t sbase = (size_t)bd*NCHUNK;
  for (int c=0;c<NCHUNK;c++){
    float ho = hbuf[base + c*NST];
    float dp = exp2f(mA2 * sdtb[sbase + c]);   // exact chunk decay product
    hbuf[base + c*NST] = hrun;                  // h_in for chunk c
    hrun = dp*hrun + ho;
  }
}

__global__ __launch_bounds__(256) void scan_pass3(
    const u16* __restrict__ dtb, const u16* __restrict__ xbf,
    const float* __restrict__ Bm, const float* __restrict__ Cm,
    const float* __restrict__ A_log, const float* __restrict__ Dvec,
    const float* __restrict__ hbuf, u16* __restrict__ ybf)
{
  int tid = blockIdx.x*256 + threadIdx.x;
  int d  = tid & (DM-1);
  int bc = tid >> 11;
  int c  = bc & (NCHUNK-1);
  int b  = bc >> 5;
  int head = d >> 6;
  float mA2[NST];
#pragma unroll
  for (int n=0;n<NST;n++)
    mA2[n] = -__expf(A_log[head*NST+n]) * 1.44269504088896341f;
  float h[NST];
  const float* hp = &hbuf[((size_t)(b*DM + d)*NCHUNK + c)*NST];
#pragma unroll
  for (int n=0;n<NST;n++) h[n] = hp[n];
  float Dv = Dvec[d];
  int rowbase = b*SEQ + c*CLEN;
  for (int t=0;t<CLEN;t++){
    int row = rowbase + t;
    float dtv = b2f(dtb[(size_t)row*DM + d]);
    float xv  = b2f(xbf[(size_t)row*DM + d]);
    float dtx = dtv*xv;
    const float4* bp = (const float4*)&Bm[(size_t)row*NST];
    const float4* cp = (const float4*)&Cm[(size_t)row*NST];
    float4 b0=bp[0],b1=bp[1],b2=bp[2],b3=bp[3];
    float4 c0=cp[0],c1=cp[1],c2=cp[2],c3=cp[3];
    float bb[NST] = {b0.x,b0.y,b0.z,b0.w, b1.x,b1.y,b1.z,b1.w,
                     b2.x,b2.y,b2.z,b2.w, b3.x,b3.y,b3.z,b3.w};
    float cc[NST] = {c0.x,c0.y,c0.z,c0.w, c1.x,c1.y,c1.z,c1.w,
                     c2.x,c2.y,c2.z,c2.w, c3.x,c3.y,c3.z,c3.w};
    float y = 0.f;
#pragma unroll
    for (int n=0;n<NST;n++){
      h[n] = exp2f(dtv*mA2[n])*h[n] + dtx*bb[n];
      y += h[n]*cc[n];
    }
    y += xv*Dv;
    ybf[(size_t)row*DM + d] = f2b(y);
  }
}

// ---------------------------------------------------------------------------
extern "C" void kernel_launch(void* const* d_in, const int* in_sizes, int n_in,
                              void* d_out, int out_size, void* d_ws, size_t ws_size,
                              hipStream_t stream)
{
  (void)in_sizes; (void)n_in; (void)out_size; (void)ws_size;
  const float* x_norm    = (const float*)d_in[0];
  const float* x_proj_w  = (const float*)d_in[1];
  const float* dt_proj_w = (const float*)d_in[2];
  const float* dt_proj_b = (const float*)d_in[3];
  const float* B_proj_w  = (const float*)d_in[4];
  const float* C_proj_w  = (const float*)d_in[5];
  const float* A_log     = (const float*)d_in[6];
  const float* Dvec      = (const float*)d_in[7];
  const float* out_w     = (const float*)d_in[8];
  float* out = (float*)d_out;
  char* ws = (char*)d_ws;

  size_t off = 0;
  auto take = [&](size_t bytes)->void*{
    void* p = ws + off; off += (bytes + 255) & ~(size_t)255; return p;
  };
  u16*   xb     = (u16*)  take((size_t)MROWS*DMODEL*2);    // x_norm bf16
  u16*   wstack = (u16*)  take((size_t)NSTACK*DMODEL*2);   // [x;dt;B;C;pad] bf16
  u16*   woutb  = (u16*)  take((size_t)DM*DM*2);           // out_proj_w bf16
  u16*   xssmb  = (u16*)  take((size_t)MROWS*DM*2);        // x_ssm bf16
  u16*   dtb    = (u16*)  take((size_t)MROWS*DM*2);        // dt bf16
  float* bcraw  = (float*)take((size_t)MROWS*32*4);        // raw B,C f32
  float* Bmb    = (float*)take((size_t)MROWS*NST*4);
  float* Cmb    = (float*)take((size_t)MROWS*NST*4);
  float* hbuf   = (float*)take((size_t)BATCH*DM*NCHUNK*NST*4);
  float* sdtb   = (float*)take((size_t)BATCH*DM*NCHUNK*4);
  u16*   ybf    = (u16*)  take((size_t)MROWS*DM*2);        // y bf16

  cvt_bf16<<<MROWS*DMODEL/1024, 256, 0, stream>>>(x_norm, xb);
  cvt_bf16<<<DM*DMODEL/1024,    256, 0, stream>>>(x_proj_w,  wstack);
  cvt_bf16<<<DM*DMODEL/1024,    256, 0, stream>>>(dt_proj_w, wstack + (size_t)DM*DMODEL);
  cvt_bf16<<<NST*DMODEL/1024,   256, 0, stream>>>(B_proj_w,  wstack + (size_t)2*DM*DMODEL);
  cvt_bf16<<<NST*DMODEL/1024,   256, 0, stream>>>(C_proj_w,  wstack + ((size_t)2*DM+16)*DMODEL);
  cvt_bf16<<<DM*DM/1024,        256, 0, stream>>>(out_w, woutb);
  // fused x_ssm + dt + B + C projection: N = 4224, K = DMODEL
  gemm_bt<3><<<dim3(NSTACK/128, MROWS/128), 256, 0, stream>>>(
      xb, wstack, bcraw, xssmb, dtb, dt_proj_b, NSTACK, DMODEL);
  bc_norm<<<MROWS*32/256, 256, 0, stream>>>(bcraw, Bmb, Cmb);
  scan_pass1<<<BATCH*NCHUNK*DM/256, 256, 0, stream>>>(dtb, xssmb, Bmb, A_log, hbuf, sdtb);
  scan_pass2<<<BATCH*DM*NST/256,    256, 0, stream>>>(hbuf, sdtb, A_log);
  scan_pass3<<<BATCH*NCHUNK*DM/256, 256, 0, stream>>>(dtb, xssmb, Bmb, Cmb, A_log, Dvec, hbuf, ybf);
  gemm_bt<2><<<dim3(DM/128, MROWS/128), 256, 0, stream>>>(ybf, woutb, out, nullptr, nullptr, nullptr, DM, DM);
}

// Round 5
// 529.320 us; speedup vs baseline: 1.7232x; 1.0645x over previous
//
#include <hip/hip_runtime.h>

typedef unsigned short u16;
typedef __attribute__((ext_vector_type(8))) short s16x8;
typedef __attribute__((ext_vector_type(4))) float f32x4;
typedef __attribute__((ext_vector_type(4))) unsigned short u16x4;

#define BATCH 4
#define SEQ 2048
#define DMODEL 1024
#define DM 2048
#define NST 16
#define NH 32
#define MROWS (BATCH*SEQ)      // 8192
#define NCHUNK 32
#define CLEN (SEQ/NCHUNK)      // 64
#define NSTACK (2*DM + 128)    // 4224 = 33 tiles of 128; cols 4096..4127 = B,C

__device__ __forceinline__ u16 f2b(float f){
  union { float f; unsigned u; } v; v.f = f;
  unsigned r = (v.u + 0x7fffu + ((v.u >> 16) & 1u)) >> 16;   // RNE
  return (u16)r;
}
__device__ __forceinline__ float b2f(u16 u){
  union { unsigned u; float f; } v; v.u = ((unsigned)u) << 16;
  return v.f;
}

// async global->LDS, 16B per lane; lptr must be wave-uniform [m97/m104]
__device__ __forceinline__ void async_ld16(const u16* g, u16* l){
  __builtin_amdgcn_global_load_lds(
      (const __attribute__((address_space(1))) void*)g,
      (__attribute__((address_space(3))) void*)l, 16, 0, 0);
}

// ---------------- fused f32 -> bf16 convert of ALL inputs ------------------
// flat float4-index regions:
//  [0, 2097152)          x_norm   -> xb
//  [2097152, 2621440)    x_proj_w -> wstack[0..)
//  [2621440, 3145728)    dt_proj_w-> wstack (dest off = i-2097152, contiguous)
//  [3145728, 4194304)    out_w    -> woutb
//  [4194304, 4198400)    B_proj_w -> wstack off 1048576 (dest = i-3145728)
//  [4198400, 4202496)    C_proj_w -> wstack off 1052672 (dest = i-3145728)
__global__ __launch_bounds__(256) void cvt_all(
    const float* __restrict__ x_norm, const float* __restrict__ xpw,
    const float* __restrict__ dtw, const float* __restrict__ outw,
    const float* __restrict__ Bw, const float* __restrict__ Cw,
    u16* __restrict__ xb, u16* __restrict__ wstack, u16* __restrict__ woutb)
{
  long i = (long)blockIdx.x*256 + threadIdx.x;
  const float* s; u16* d; long so, dofs;
  if (i < 2097152L)      { s = x_norm; d = xb;     so = i;            dofs = i; }
  else if (i < 2621440L) { s = xpw;    d = wstack; so = i - 2097152L; dofs = i - 2097152L; }
  else if (i < 3145728L) { s = dtw;    d = wstack; so = i - 2621440L; dofs = i - 2097152L; }
  else if (i < 4194304L) { s = outw;   d = woutb;  so = i - 3145728L; dofs = i - 3145728L; }
  else if (i < 4198400L) { s = Bw;     d = wstack; so = i - 4194304L; dofs = i - 3145728L; }
  else                   { s = Cw;     d = wstack; so = i - 4198400L; dofs = i - 3145728L; }
  float4 v = ((const float4*)s)[so];
  u16x4 o; o[0]=f2b(v.x); o[1]=f2b(v.y); o[2]=f2b(v.z); o[3]=f2b(v.w);
  ((u16x4*)d)[dofs] = o;
}

// ---------------- bf16 MFMA GEMM: C[M,N] = A[M,K] @ W[N,K]^T ---------------
// 128x128 tile, BK=32, DOUBLE-BUFFERED async global_load_lds staging.
// LDS: unpadded [row][32] shorts, XOR-swizzled 16B k-segments (conflict-free).
// XCD swizzle: bid&7 -> XCD (round-robin heuristic); each XCD owns 8
// consecutive by (A-chunk L2-resident), bx outer within XCD.
// EPI: 2 = store f32 (final out)
//      3 = fused proj split: [0,DM) x_ssm bf16; [DM,2DM) dt bf16 (cheap exact
//          softplus); [2DM,2DM+32) B/C with in-register L2-normalize; pad skip
template<int EPI>
__global__ __launch_bounds__(256) void gemm_bt(
    const u16* __restrict__ A, const u16* __restrict__ W,
    float* __restrict__ Cf, u16* __restrict__ Cb, u16* __restrict__ Cb2,
    float* __restrict__ Bm, float* __restrict__ Cm,
    const float* __restrict__ bias, int N, int K)
{
  __shared__ u16 As[2][128*32];
  __shared__ u16 Ws[2][128*32];
  const int tid  = threadIdx.x;
  const int lane = tid & 63;
  const int wave = tid >> 6;
  const int qk = lane >> 4;     // k-quad: k = qk*8 + j
  const int rl = lane & 15;     // m/n within 16-tile
  const int qs = qk ^ ((rl >> 1) & 3);   // swizzled k-seg for fragment reads
  const int wm = (wave >> 1) << 6;
  const int wn = (wave & 1) << 6;

  // XCD-locality block swizzle (gy == 64 on both call sites)
  const int gx = gridDim.x;
  const int bid = blockIdx.y * gx + blockIdx.x;
  const int x8 = bid & 7;
  const int j  = bid >> 3;
  const int by = x8 * 8 + (j & 7);
  const int bx = j >> 3;
  const int rowA0 = by * 128;
  const int rowW0 = bx * 128;

  f32x4 acc[4][4];
#pragma unroll
  for (int mi=0;mi<4;mi++)
#pragma unroll
    for (int ni=0;ni<4;ni++)
      acc[mi][ni] = (f32x4){0.f,0.f,0.f,0.f};

  const int gr0 = wave * 32;
  const int slog = (lane & 3) ^ ((lane >> 3) & 3);     // swizzled global seg
  const u16* Ag = A + (size_t)(rowA0 + gr0 + (lane>>2))*K + slog*8;
  const u16* Wg = W + (size_t)(rowW0 + gr0 + (lane>>2))*K + slog*8;
  const size_t rstep16 = (size_t)16*K;   // row+16: (row>>1)&3 unchanged -> same slog

  u16* AsD0[2] = { &As[0][gr0*32], &As[1][gr0*32] };
  u16* AsD1[2] = { &As[0][(gr0+16)*32], &As[1][(gr0+16)*32] };
  u16* WsD0[2] = { &Ws[0][gr0*32], &Ws[1][gr0*32] };
  u16* WsD1[2] = { &Ws[0][(gr0+16)*32], &Ws[1][(gr0+16)*32] };

  // prologue: stage k-step 0 into buf 0
  async_ld16(Ag,           AsD0[0]);
  async_ld16(Ag + rstep16, AsD1[0]);
  async_ld16(Wg,           WsD0[0]);
  async_ld16(Wg + rstep16, WsD1[0]);

  const int S = K >> 5;
  for (int s = 0; s < S; s++){
    const int cur = s & 1;
    __syncthreads();   // drains own async loads (buf cur) + everyone done
                       // reading buf cur^1 from step s-1 -> safe to refill it
    if (s + 1 < S){
      const int k1 = (s+1) << 5;
      async_ld16(Ag + k1,           AsD0[cur^1]);
      async_ld16(Ag + rstep16 + k1, AsD1[cur^1]);
      async_ld16(Wg + k1,           WsD0[cur^1]);
      async_ld16(Wg + rstep16 + k1, WsD1[cur^1]);
    }
    s16x8 af[4], bfr[4];
#pragma unroll
    for (int mi=0;mi<4;mi++) af[mi]  = *(const s16x8*)&As[cur][(wm + mi*16 + rl)*32 + qs*8];
#pragma unroll
    for (int ni=0;ni<4;ni++) bfr[ni] = *(const s16x8*)&Ws[cur][(wn + ni*16 + rl)*32 + qs*8];
#pragma unroll
    for (int mi=0;mi<4;mi++)
#pragma unroll
      for (int ni=0;ni<4;ni++)
        acc[mi][ni] = __builtin_amdgcn_mfma_f32_16x16x32_bf16(af[mi], bfr[ni], acc[mi][ni], 0, 0, 0);
  }

  // C/D layout: col = lane&15, row = (lane>>4)*4 + reg   [m89/m91 verified]
  const int crow = rowA0 + wm + qk*4;
  const int ccol = rowW0 + wn + rl;
#pragma unroll
  for (int mi=0;mi<4;mi++){
#pragma unroll
    for (int ni=0;ni<4;ni++){
      const int col = ccol + ni*16;
#pragma unroll
      for (int r=0;r<4;r++){
        const int row = crow + mi*16 + r;
        float v = acc[mi][ni][r];
        if constexpr (EPI == 2){
          Cf[(size_t)row*N + col] = v;
        } else {   // EPI == 3 (all branches wave-uniform: 16-aligned splits)
          if (col < DM){
            Cb[(size_t)row*DM + col] = f2b(v);
          } else if (col < 2*DM){
            int cc = col - DM;
            float t = v + bias[cc];
            t = fminf(fmaxf(t, -9.22f), -2.2521684f);
            float x = __expf(t);                       // <= 0.10517
            float sp = x*(1.f - x*(0.5f - x*(0.33333333f - x*0.25f)));
            sp = fminf(fmaxf(sp, 1e-4f), 0.1f);
            Cb2[(size_t)row*DM + cc] = f2b(sp);
          } else if (col < 2*DM + 32){
            // B (cols 2DM..2DM+15) / C (2DM+16..2DM+31): L2-normalize across
            // the 16-lane rl group (same row within the group) in-register.
            float ss = v*v;
            ss += __shfl_xor(ss, 1, 64);
            ss += __shfl_xor(ss, 2, 64);
            ss += __shfl_xor(ss, 4, 64);
            ss += __shfl_xor(ss, 8, 64);
            float o = v / fmaxf(sqrtf(ss), 1.0f);
            float* dst = (col < 2*DM + 16) ? Bm : Cm;
            dst[(size_t)row*NST + rl] = o;
          }
          // else: padding columns (garbage weights) — never stored
        }
      }
    }
  }
}

// ---------------- selective scan: 3-pass chunked --------------------------
// hbuf layout: [b][c][d][n]  (thread-contiguous 64B chunks, wave-coalesced)
// sdtb layout: [b][c][d]
__global__ __launch_bounds__(256) void scan_pass1(
    const u16* __restrict__ dtb, const u16* __restrict__ xbf,
    const float* __restrict__ Bm, const float* __restrict__ A_log,
    float* __restrict__ hbuf, float* __restrict__ sdtb)
{
  int tid = blockIdx.x*256 + threadIdx.x;   // (b*NCHUNK + c)*DM + d
  int d  = tid & (DM-1);
  int bc = tid >> 11;
  int c  = bc & (NCHUNK-1);
  int b  = bc >> 5;
  int head = d >> 6;                        // DM/NH = 64 channels per head
  float mA2[NST];
#pragma unroll
  for (int n=0;n<NST;n++)
    mA2[n] = -__expf(A_log[head*NST+n]) * 1.44269504088896341f;  // -A*log2(e)
  float h[NST];
#pragma unroll
  for (int n=0;n<NST;n++) h[n] = 0.f;
  float sdt = 0.f;
  int rowbase = b*SEQ + c*CLEN;
  for (int t=0;t<CLEN;t++){
    int row = rowbase + t;
    float dtv = b2f(dtb[(size_t)row*DM + d]);
    float xv  = b2f(xbf[(size_t)row*DM + d]);
    sdt += dtv;
    float dtx = dtv*xv;
    const float4* bp = (const float4*)&Bm[(size_t)row*NST];
    float4 b0=bp[0],b1=bp[1],b2=bp[2],b3=bp[3];
    float bb[NST] = {b0.x,b0.y,b0.z,b0.w, b1.x,b1.y,b1.z,b1.w,
                     b2.x,b2.y,b2.z,b2.w, b3.x,b3.y,b3.z,b3.w};
#pragma unroll
    for (int n=0;n<NST;n++)
      h[n] = exp2f(dtv*mA2[n])*h[n] + dtx*bb[n];
  }
  float* hp = &hbuf[(size_t)tid*NST];
#pragma unroll
  for (int n=0;n<NST;n++) hp[n] = h[n];
  sdtb[tid] = sdt;
}

__global__ __launch_bounds__(256) void scan_pass2(
    float* __restrict__ hbuf, const float* __restrict__ sdtb,
    const float* __restrict__ A_log)
{
  int tid = blockIdx.x*256 + threadIdx.x;   // b*DM*NST
  int n  = tid & (NST-1);
  int bd = tid >> 4;
  int d  = bd & (DM-1);
  int b  = bd >> 11;
  int head = d >> 6;
  float mA2 = -__expf(A_log[head*NST+n]) * 1.44269504088896341f;
  float hrun = 0.f;
  for (int c=0;c<NCHUNK;c++){
    size_t idx = ((size_t)((b*NCHUNK + c)*DM) + d)*NST + n;
    float ho = hbuf[idx];
    float dp = exp2f(mA2 * sdtb[(size_t)(b*NCHUNK + c)*DM + d]);
    hbuf[idx] = hrun;                  // h_in for chunk c
    hrun = dp*hrun + ho;
  }
}

__global__ __launch_bounds__(256) void scan_pass3(
    const u16* __restrict__ dtb, const u16* __restrict__ xbf,
    const float* __restrict__ Bm, const float* __restrict__ Cm,
    const float* __restrict__ A_log, const float* __restrict__ Dvec,
    const float* __restrict__ hbuf, u16* __restrict__ ybf)
{
  int tid = blockIdx.x*256 + threadIdx.x;
  int d  = tid & (DM-1);
  int bc = tid >> 11;
  int c  = bc & (NCHUNK-1);
  int b  = bc >> 5;
  int head = d >> 6;
  float mA2[NST];
#pragma unroll
  for (int n=0;n<NST;n++)
    mA2[n] = -__expf(A_log[head*NST+n]) * 1.44269504088896341f;
  float h[NST];
  const float* hp = &hbuf[(size_t)tid*NST];
#pragma unroll
  for (int n=0;n<NST;n++) h[n] = hp[n];
  float Dv = Dvec[d];
  int rowbase = b*SEQ + c*CLEN;
  for (int t=0;t<CLEN;t++){
    int row = rowbase + t;
    float dtv = b2f(dtb[(size_t)row*DM + d]);
    float xv  = b2f(xbf[(size_t)row*DM + d]);
    float dtx = dtv*xv;
    const float4* bp = (const float4*)&Bm[(size_t)row*NST];
    const float4* cp = (const float4*)&Cm[(size_t)row*NST];
    float4 b0=bp[0],b1=bp[1],b2=bp[2],b3=bp[3];
    float4 c0=cp[0],c1=cp[1],c2=cp[2],c3=cp[3];
    float bb[NST] = {b0.x,b0.y,b0.z,b0.w, b1.x,b1.y,b1.z,b1.w,
                     b2.x,b2.y,b2.z,b2.w, b3.x,b3.y,b3.z,b3.w};
    float cc[NST] = {c0.x,c0.y,c0.z,c0.w, c1.x,c1.y,c1.z,c1.w,
                     c2.x,c2.y,c2.z,c2.w, c3.x,c3.y,c3.z,c3.w};
    float y = 0.f;
#pragma unroll
    for (int n=0;n<NST;n++){
      h[n] = exp2f(dtv*mA2[n])*h[n] + dtx*bb[n];
      y += h[n]*cc[n];
    }
    y += xv*Dv;
    ybf[(size_t)row*DM + d] = f2b(y);
  }
}

// ---------------------------------------------------------------------------
extern "C" void kernel_launch(void* const* d_in, const int* in_sizes, int n_in,
                              void* d_out, int out_size, void* d_ws, size_t ws_size,
                              hipStream_t stream)
{
  (void)in_sizes; (void)n_in; (void)out_size; (void)ws_size;
  const float* x_norm    = (const float*)d_in[0];
  const float* x_proj_w  = (const float*)d_in[1];
  const float* dt_proj_w = (const float*)d_in[2];
  const float* dt_proj_b = (const float*)d_in[3];
  const float* B_proj_w  = (const float*)d_in[4];
  const float* C_proj_w  = (const float*)d_in[5];
  const float* A_log     = (const float*)d_in[6];
  const float* Dvec      = (const float*)d_in[7];
  const float* out_w     = (const float*)d_in[8];
  float* out = (float*)d_out;
  char* ws = (char*)d_ws;

  size_t off = 0;
  auto take = [&](size_t bytes)->void*{
    void* p = ws + off; off += (bytes + 255) & ~(size_t)255; return p;
  };
  u16*   xb     = (u16*)  take((size_t)MROWS*DMODEL*2);    // x_norm bf16
  u16*   wstack = (u16*)  take((size_t)NSTACK*DMODEL*2);   // [x;dt;B;C;pad] bf16
  u16*   woutb  = (u16*)  take((size_t)DM*DM*2);           // out_proj_w bf16
  u16*   xssmb  = (u16*)  take((size_t)MROWS*DM*2);        // x_ssm bf16
  u16*   dtb    = (u16*)  take((size_t)MROWS*DM*2);        // dt bf16
  float* Bmb    = (float*)take((size_t)MROWS*NST*4);
  float* Cmb    = (float*)take((size_t)MROWS*NST*4);
  float* hbuf   = (float*)take((size_t)BATCH*DM*NCHUNK*NST*4);
  float* sdtb   = (float*)take((size_t)BATCH*DM*NCHUNK*4);
  u16*   ybf    = (u16*)  take((size_t)MROWS*DM*2);        // y bf16

  cvt_all<<<16416, 256, 0, stream>>>(x_norm, x_proj_w, dt_proj_w, out_w,
                                     B_proj_w, C_proj_w, xb, wstack, woutb);
  // fused x_ssm + dt + B + C projection (+softplus + B/C normalize): N=4224
  gemm_bt<3><<<dim3(NSTACK/128, MROWS/128), 256, 0, stream>>>(
      xb, wstack, nullptr, xssmb, dtb, Bmb, Cmb, dt_proj_b, NSTACK, DMODEL);
  scan_pass1<<<BATCH*NCHUNK*DM/256, 256, 0, stream>>>(dtb, xssmb, Bmb, A_log, hbuf, sdtb);
  scan_pass2<<<BATCH*DM*NST/256,    256, 0, stream>>>(hbuf, sdtb, A_log);
  scan_pass3<<<BATCH*NCHUNK*DM/256, 256, 0, stream>>>(dtb, xssmb, Bmb, Cmb, A_log, Dvec, hbuf, ybf);
  gemm_bt<2><<<dim3(DM/128, MROWS/128), 256, 0, stream>>>(
      ybf, woutb, out, nullptr, nullptr, nullptr, nullptr, nullptr, DM, DM);
}